// Round 8
// baseline (1198.769 us; speedup 1.0000x reference)
//
#include <hip/hip_runtime.h>

#define NROW 5000
#define NPAD 5120   // padded rows
#define KW   80     // u64 words per padded row
#define KC   80     // 64-k chunks
#define KZ   4      // split-K
#define KCQ  20     // chunks per split
#define HDIM 128
#define FXS  4194304.0f                  // 2^22 fixed-point scale
#define PART ((size_t)4 * NROW * HDIM)   // agg elements per kz part

typedef _Float16 f16x8 __attribute__((ext_vector_type(8)));
typedef float f32x16 __attribute__((ext_vector_type(16)));

__device__ __forceinline__ unsigned short f2h_int(int v) {   // exact for |v| <= 2048
    union { _Float16 h; unsigned short u; } c;
    c.h = (_Float16)(float)v;
    return c.u;
}
// q = round(h*2^22); digits base 2048: q == d1*2048 + d0
__device__ __forceinline__ void fx_digits(float h, unsigned short& d1, unsigned short& d0) {
    int q = (int)rintf(h * FXS);
    d1 = f2h_int(q >> 11);
    d0 = f2h_int(q & 2047);
}

// Fragment-major B layout: element (kc, pl, kk, half, col, j) holds digit plane pl of
// k = kc*64 + kk*16 + half*8 + j for column col. strides in f16 units: kc 16384,
// pl 8192, kk 2048, half 1024, col 8.
__device__ __forceinline__ size_t bt_idx(int kc, int pl, int kk, int half, int col, int j) {
    return (((((size_t)kc * 2 + pl) * 4 + kk) * 2 + half) * 128 + col) * 8 + j;
}

// Fragment-major dense-A layout (f16 0/1): element ((e,kc,kk,half), row, j), j=0..7.
// f16 strides: half 40960 (=NPAD*8), kk 81920, kc 327680, e 26214400; row 8.
__device__ __forceinline__ size_t at_idx(int e, int kc, int kk, int half, int row, int j) {
    return ((((size_t)(e * KC + kc) * 4 + kk) * 2 + half) * NPAD + row) * 8 + j;
}

// ---- prep: resolve atom indices; detect int32 vs int64 storage device-side ----
__global__ __launch_bounds__(256) void prep_atom_kernel(const unsigned int* __restrict__ atomw,
                                                        int* __restrict__ atomIdx) {
    __shared__ int s_is64;
    if (threadIdx.x == 0) {
        bool all0 = true, anynz = false;
        for (int j = 0; j < 64; ++j) {
            unsigned lo = atomw[2 * j], hi = atomw[2 * j + 1];
            all0 = all0 && (hi == 0u);
            anynz = anynz || (lo != 0u);
        }
        s_is64 = (all0 && anynz) ? 1 : 0;
    }
    __syncthreads();
    int v = blockIdx.x * 256 + threadIdx.x;
    if (v < NROW) atomIdx[v] = s_is64 ? (int)atomw[2 * v] : (int)atomw[v];
}

// ---- prep: bit-pack adjacency, ROW-major (one block per (e,row) = 20480 blocks, max MLP) ----
__global__ __launch_bounds__(256) void prep_pack_kernel(const int* __restrict__ adjs,
                                                        unsigned long long* __restrict__ packedR) {
    const int er = blockIdx.x;            // [0, 4*NPAD)
    const int e = er / NPAD;
    const int r = er - e * NPAD;
    const int wave = threadIdx.x >> 6;
    const int lane = threadIdx.x & 63;
    const int* rowp = adjs + ((size_t)e * NROW + r) * NROW;
    unsigned long long* outp = packedR + ((size_t)e * NPAD + r) * KW;
    const bool rok = (r < NROW);
    for (int c = wave; c < KW; c += 4) {
        int u = c * 64 + lane;
        int val = (rok && u < NROW) ? rowp[u] : 0;
        unsigned long long m = __ballot(val == 1);
        if (lane == 0) outp[c] = m;
    }
}

// ---- prep: transpose packed bits row-major -> kc-major via LDS (coalesced both sides) ----
__global__ __launch_bounds__(256) void prep_packT_kernel(const unsigned long long* __restrict__ packedR,
                                                         unsigned long long* __restrict__ packedT) {
    __shared__ unsigned long long slds[64][KW + 1];   // 41.5 KB, pad breaks bank alias
    const int e = blockIdx.y;
    const int r0 = blockIdx.x * 64;
    const int tid = threadIdx.x;
#pragma unroll
    for (int p = 0; p < 20; ++p) {        // 64 r x 80 c = 5120 words / 256 thr
        int idx = p * 256 + tid;
        int r = idx / KW;
        int c = idx - r * KW;
        slds[r][c] = packedR[((size_t)e * NPAD + r0 + r) * KW + c];
    }
    __syncthreads();
#pragma unroll
    for (int p = 0; p < 20; ++p) {
        int idx = p * 256 + tid;
        int kc = idx >> 6;
        int rr = idx & 63;
        packedT[((size_t)e * KC + kc) * NPAD + r0 + rr] = slds[rr][kc];
    }
}

// ---- prep: expand packed bits -> dense f16 0/1 A in MFMA-fragment order (once per call) ----
// Thread -> one (row, e, kc, kk, half): reads one byte of the packed word, writes 16 B.
__global__ __launch_bounds__(256) void prep_Aexp_kernel(const unsigned long long* __restrict__ packedR,
                                                        unsigned short* __restrict__ At) {
    const int row = blockIdx.x * 256 + threadIdx.x;   // < NPAD
    const int kc = blockIdx.y;                        // < KC
    const int z = blockIdx.z;                         // e*8 + kk*2 + half
    const int e = z >> 3;
    const int kk = (z >> 2) & 1 ? 0 : 0;              // placeholder (recomputed below)
    const int kh = z & 7;
    const int kk2 = kh >> 1;
    const int half = kh & 1;
    (void)kk;
    unsigned long long word = packedR[((size_t)e * NPAD + row) * KW + kc];
    unsigned int b = (unsigned int)(word >> (kk2 * 16 + half * 8)) & 0xFFu;
    unsigned int y = b | (b << 15);
    uint4 u;
    u.x = ((y >> 0) & 0x00010001u) * 0x3C00u;
    u.y = ((y >> 2) & 0x00010001u) * 0x3C00u;
    u.z = ((y >> 4) & 0x00010001u) * 0x3C00u;
    u.w = ((y >> 6) & 0x00010001u) * 0x3C00u;
    *(uint4*)&At[at_idx(e, kc, kk2, half, row, 0)] = u;
}

// ------- prep: h0 -> fragment-major f16 digit planes from fp32 embedding -------
__global__ __launch_bounds__(256) void prep_h0T_kernel(const int* __restrict__ atomIdx,
                                                       const float* __restrict__ emb,
                                                       unsigned short* __restrict__ hTt) {
    const int i = blockIdx.y;
    const int v = blockIdx.x * 256 + threadIdx.x;   // < NPAD (k index)
    float val = 0.f;
    if (v < NROW) val = emb[(size_t)atomIdx[v] * HDIM + i];
    unsigned short d1, d0;
    fx_digits(val, d1, d0);
    const int kc = v >> 6, kk = (v >> 4) & 3, half = (v >> 3) & 1, j = v & 7;
    hTt[bt_idx(kc, 0, kk, half, i, j)] = d1;
    hTt[bt_idx(kc, 1, kk, half, i, j)] = d0;
}

// ---------------- prep: h0 fp32 row-major state ----------------
__global__ __launch_bounds__(256) void prep_h0f_kernel(const int* __restrict__ atomIdx,
                                                       const float* __restrict__ emb,
                                                       float* __restrict__ h) {
    int idx = blockIdx.x * 256 + threadIdx.x;   // < NROW*HDIM
    int v = idx >> 7, i = idx & 127;
    h[idx] = emb[(size_t)atomIdx[v] * HDIM + i];
}

// ---------------- prep: Htr[(e*128+j)*128 + i] = H[e][i][j] (fp32) ----------------
__global__ __launch_bounds__(256) void prep_Ht_kernel(const float* __restrict__ H,
                                                      float* __restrict__ Htr) {
    int idx = blockIdx.x * 256 + threadIdx.x;   // < 4*128*128
    int e = idx >> 14;
    int j = (idx >> 7) & 127;
    int i = idx & 127;
    Htr[idx] = H[((size_t)e * HDIM + i) * HDIM + j];
}

// ---- GEMM1 dense (EXACT, pure load->MFMA, zero expansion VALU): agg = A * h ----
// 512 thr = 8 waves: wm row-half, wc col-tile; block tile 128x128; MTI=2.
// A from dense fragment-major f16 (0/1) — identical values/order to bit path.
__global__ __launch_bounds__(512, 4) void gemm1_dense_kernel(const unsigned short* __restrict__ At,
                                                             const unsigned short* __restrict__ hTt,
                                                             float* __restrict__ agg) {
    const int m0 = blockIdx.x * 128;
    const int e = blockIdx.y;
    const int kz = blockIdx.z;
    const int tid = threadIdx.x;
    const int lane = tid & 63;
    const int wave = tid >> 6;           // 0..7
    const int wm = wave >> 2;            // 0..1 row-half
    const int wc = wave & 3;             // 0..3 col-tile
    const int l31 = lane & 31;
    const int l1 = lane >> 5;            // half-wave selector
    const int col = wc * 32 + l31;
    const int kc0 = kz * KCQ;

    f32x16 acc[2][2];                    // [pl][mt] = 64 regs
#pragma unroll
    for (int pl = 0; pl < 2; ++pl)
#pragma unroll
        for (int mt = 0; mt < 2; ++mt) acc[pl][mt] = (f32x16)(0.f);

    // A: row = m0 + wm*64 + mt*32 + l31, fragment (kk, half=l1)
    const _Float16* aD = (const _Float16*)At +
                         (((size_t)(e * KC + kc0) * 4) * 2 + l1) * ((size_t)NPAD * 8) +
                         (size_t)(m0 + wm * 64 + l31) * 8;
    const _Float16* bp = (const _Float16*)hTt + (size_t)kc0 * 16384 +
                         (size_t)l1 * 1024 + (size_t)col * 8;

    for (int kc = 0; kc < KCQ; ++kc) {
        f16x8 af[4][2];                  // [kk][mt]
#pragma unroll
        for (int kk = 0; kk < 4; ++kk)
#pragma unroll
            for (int mt = 0; mt < 2; ++mt)
                af[kk][mt] = *(const f16x8*)(aD + (size_t)kk * 81920 + mt * 256);

        f16x8 bf[2][4];                  // [pl][kk]
#pragma unroll
        for (int pl = 0; pl < 2; ++pl)
#pragma unroll
            for (int kk = 0; kk < 4; ++kk)
                bf[pl][kk] = *(const f16x8*)(bp + pl * 8192 + kk * 2048);

        aD += 327680;
        bp += 16384;

#pragma unroll
        for (int kk = 0; kk < 4; ++kk)
#pragma unroll
            for (int mt = 0; mt < 2; ++mt)
#pragma unroll
                for (int pl = 0; pl < 2; ++pl)
                    acc[pl][mt] = __builtin_amdgcn_mfma_f32_32x32x16_f16(
                        af[kk][mt], bf[pl][kk], acc[pl][mt], 0, 0, 0);
    }

    // epilogue: exact digit combine in double, one optimal fp32 rounding
    float* aggz = agg + (size_t)kz * PART;
#pragma unroll
    for (int mt = 0; mt < 2; ++mt)
#pragma unroll
        for (int reg = 0; reg < 16; ++reg) {
            int row = (reg & 3) + 8 * (reg >> 2) + 4 * l1;
            int v = m0 + wm * 64 + mt * 32 + row;
            if (v < NROW) {
                double d = (double)acc[0][mt][reg] * 2048.0 + (double)acc[1][mt][reg];
                aggz[((size_t)e * NROW + v) * HDIM + col] = (float)(d * (1.0 / 4194304.0));
            }
        }
}

// ---- GEMM1 bit-path fallback (round-7 kernel, used only if workspace too small) ----
__global__ __launch_bounds__(512, 4) void gemm1_bits_kernel(const unsigned long long* __restrict__ packedT,
                                                            const unsigned short* __restrict__ hTt,
                                                            float* __restrict__ agg) {
    const int m0 = blockIdx.x * 128;
    const int e = blockIdx.y;
    const int kz = blockIdx.z;
    const int tid = threadIdx.x;
    const int lane = tid & 63;
    const int wave = tid >> 6;
    const int wm = wave >> 2;
    const int wc = wave & 3;
    const int l31 = lane & 31;
    const int l1 = lane >> 5;
    const int sh2 = l1 * 8;
    const int col = wc * 32 + l31;
    const int kc0 = kz * KCQ;

    f32x16 acc[2][2];
#pragma unroll
    for (int pl = 0; pl < 2; ++pl)
#pragma unroll
        for (int mt = 0; mt < 2; ++mt) acc[pl][mt] = (f32x16)(0.f);

    const unsigned long long* ap = packedT + ((size_t)e * KC + kc0) * NPAD + m0 + wm * 64 + l31;
    const _Float16* bp = (const _Float16*)hTt + (size_t)kc0 * 16384 +
                         (size_t)l1 * 1024 + (size_t)col * 8;

    for (int kc = 0; kc < KCQ; ++kc) {
        unsigned long long aw[2];
        aw[0] = ap[0];
        aw[1] = ap[32];
        f16x8 bf[2][4];
#pragma unroll
        for (int pl = 0; pl < 2; ++pl)
#pragma unroll
            for (int kk = 0; kk < 4; ++kk)
                bf[pl][kk] = *(const f16x8*)(bp + pl * 8192 + kk * 2048);
        ap += NPAD;
        bp += 16384;
#pragma unroll
        for (int kk = 0; kk < 4; ++kk) {
#pragma unroll
            for (int mt = 0; mt < 2; ++mt) {
                unsigned int w = (kk < 2) ? (unsigned int)aw[mt] : (unsigned int)(aw[mt] >> 32);
                unsigned int b = (w >> ((kk & 1) * 16 + sh2)) & 0xFFu;
                unsigned int y = b | (b << 15);
                union { unsigned int u[4]; f16x8 h; } Af;
#pragma unroll
                for (int q = 0; q < 4; ++q)
                    Af.u[q] = ((y >> (2 * q)) & 0x00010001u) * 0x3C00u;
#pragma unroll
                for (int pl = 0; pl < 2; ++pl)
                    acc[pl][mt] = __builtin_amdgcn_mfma_f32_32x32x16_f16(
                        Af.h, bf[pl][kk], acc[pl][mt], 0, 0, 0);
            }
        }
    }

    float* aggz = agg + (size_t)kz * PART;
#pragma unroll
    for (int mt = 0; mt < 2; ++mt)
#pragma unroll
        for (int reg = 0; reg < 16; ++reg) {
            int row = (reg & 3) + 8 * (reg >> 2) + 4 * l1;
            int v = m0 + wm * 64 + mt * 32 + row;
            if (v < NROW) {
                double d = (double)acc[0][mt][reg] * 2048.0 + (double)acc[1][mt][reg];
                aggz[((size_t)e * NROW + v) * HDIM + col] = (float)(d * (1.0 / 4194304.0));
            }
        }
}

// --- GEMM2: msg[v][i] = sum_ej Htr[ej][i]*agg[v][ej], sigmoid, fp32 out + digits ---
__global__ __launch_bounds__(256) void gemm2_kernel(const float* __restrict__ agg,
                                                    const float* __restrict__ Htr,
                                                    float* __restrict__ hf,       // fp32 state, in/out
                                                    float* __restrict__ outp,     // d_out slice t (fp32)
                                                    unsigned short* __restrict__ hTt) {
    __shared__ float aggs[8][512];             // 16 KB
    __shared__ unsigned short hs[2][128][8];   // 4 KB digit transpose buffers
    const int tid = threadIdx.x;
    const int v0 = blockIdx.x * 8;             // < 5000 always (625*8 = 5000)

#pragma unroll
    for (int it = 0; it < 4; ++it) {
        int idx = it * 256 + tid;          // float4 index, 0..1023
        int r = idx >> 7;
        int c = (idx & 127) * 4;
        int e = c >> 7, j = c & 127;
        size_t o = ((size_t)e * NROW + (v0 + r)) * HDIM + j;
        float4 a0 = *(const float4*)&agg[o];
        float4 a1 = *(const float4*)&agg[PART + o];
        float4 a2 = *(const float4*)&agg[2 * PART + o];
        float4 a3 = *(const float4*)&agg[3 * PART + o];
        *(float4*)&aggs[r][c] = make_float4((a0.x + a1.x) + (a2.x + a3.x),
                                            (a0.y + a1.y) + (a2.y + a3.y),
                                            (a0.z + a1.z) + (a2.z + a3.z),
                                            (a0.w + a1.w) + (a2.w + a3.w));
    }
    __syncthreads();

    const int ip = tid & 63;
    const int vg = tid >> 6;             // 0..3 -> rows vg*2, vg*2+1
    const int i0 = ip * 2;

    float m[2][2][4];                    // [row][i-col][k-lane]
#pragma unroll
    for (int r = 0; r < 2; ++r)
#pragma unroll
        for (int q = 0; q < 2; ++q)
#pragma unroll
            for (int k = 0; k < 4; ++k) m[r][q][k] = 0.f;

    const int rb = vg * 2;
    for (int cg = 0; cg < 128; ++cg) {
        int c = cg * 4;
        float4 q0 = *(const float4*)&aggs[rb][c];       // broadcast, conflict-free
        float4 q1 = *(const float4*)&aggs[rb + 1][c];
        float a0v[4] = {q0.x, q0.y, q0.z, q0.w};
        float a1v[4] = {q1.x, q1.y, q1.z, q1.w};
#pragma unroll
        for (int k = 0; k < 4; ++k) {
            float2 w = *(const float2*)&Htr[(size_t)(c + k) * HDIM + i0];
            m[0][0][k] += a0v[k] * w.x;
            m[0][1][k] += a0v[k] * w.y;
            m[1][0][k] += a1v[k] * w.x;
            m[1][1][k] += a1v[k] * w.y;
        }
    }

#pragma unroll
    for (int r = 0; r < 2; ++r) {
        int vr = rb + r;
        int v = v0 + vr;
        size_t o = (size_t)v * HDIM + i0;
        float2 hv = *(const float2*)&hf[o];
        float ms0 = (m[r][0][0] + m[r][0][1]) + (m[r][0][2] + m[r][0][3]);
        float ms1 = (m[r][1][0] + m[r][1][1]) + (m[r][1][2] + m[r][1][3]);
        float x0 = hv.x + ms0;
        float x1 = hv.y + ms1;
        float s0 = 1.0f / (1.0f + expf(-x0));
        float s1 = 1.0f / (1.0f + expf(-x1));
        *(float2*)&outp[o] = make_float2(s0, s1);
        *(float2*)&hf[o] = make_float2(s0, s1);
        unsigned short d1a, d0a, d1b, d0b;
        fx_digits(s0, d1a, d0a);
        fx_digits(s1, d1b, d0b);
        hs[0][i0][vr] = d1a;
        hs[1][i0][vr] = d0a;
        hs[0][i0 + 1][vr] = d1b;
        hs[1][i0 + 1][vr] = d0b;
    }
    __syncthreads();
    if (tid < 128) {    // one uint4 (8 k-entries) per plane, coalesced
        const int kc = v0 >> 6, kk = (v0 >> 4) & 3, half = (v0 >> 3) & 1;
#pragma unroll
        for (int pl = 0; pl < 2; ++pl)
            *(uint4*)&hTt[bt_idx(kc, pl, kk, half, tid, 0)] = *(const uint4*)&hs[pl][tid][0];
    }
}

extern "C" void kernel_launch(void* const* d_in, const int* in_sizes, int n_in,
                              void* d_out, int out_size, void* d_ws, size_t ws_size,
                              hipStream_t stream) {
    const unsigned int* atomw = (const unsigned int*)d_in[0];  // int32 OR int64 — sniffed on device
    const int* adjs = (const int*)d_in[1];                     // int32
    // d_in[2] = max_time_steps; reference constant T=4 hard-coded
    const float* emb = (const float*)d_in[3];                  // fp32
    const float* H = (const float*)d_in[4];                    // fp32
    float* out = (float*)d_out;                                // fp32 output

    char* ws = (char*)d_ws;
    unsigned long long* packedT = (unsigned long long*)ws;           // 13,107,200 B (kc-major)
    size_t off = (size_t)4 * KC * NPAD * 8;
    unsigned short* hTt = (unsigned short*)(ws + off);               // 2 planes fragment-major
    off += (size_t)2 * KC * HDIM * 64 * 2;
    float* hf = (float*)(ws + off);                                  // 2,560,000 B
    off += (size_t)NROW * HDIM * 4;
    float* agg = (float*)(ws + off);                                 // 4 parts = 40,960,000 B
    off += (size_t)KZ * PART * 4;
    float* Htr = (float*)(ws + off);                                 // 262,144 B
    off += (size_t)4 * HDIM * HDIM * 4;
    int* atomIdx = (int*)(ws + off);                                 // 20,000 B
    off += (size_t)NROW * 4;
    off = (off + 255) & ~(size_t)255;
    unsigned long long* packedR = (unsigned long long*)(ws + off);   // 13,107,200 B (row-major)
    off += (size_t)4 * NPAD * KW * 8;
    unsigned short* At = (unsigned short*)(ws + off);                // dense f16 A, 209,715,200 B
    size_t off_end = off + (size_t)4 * KC * 8 * NPAD * 8 * 2;
    const bool dense = (ws_size >= off_end);                         // fills show ws ~1.6 GB

    prep_atom_kernel<<<dim3((NROW + 255) / 256), 256, 0, stream>>>(atomw, atomIdx);
    prep_pack_kernel<<<dim3(4 * NPAD), 256, 0, stream>>>(adjs, packedR);
    if (dense) {
        prep_Aexp_kernel<<<dim3(NPAD / 256, KC, 32), 256, 0, stream>>>(packedR, At);
    } else {
        prep_packT_kernel<<<dim3(NPAD / 64, 4), 256, 0, stream>>>(packedR, packedT);
    }
    prep_h0T_kernel<<<dim3(NPAD / 256, HDIM), 256, 0, stream>>>(atomIdx, emb, hTt);
    prep_h0f_kernel<<<dim3(NROW * HDIM / 256), 256, 0, stream>>>(atomIdx, emb, hf);
    prep_Ht_kernel<<<dim3(4 * HDIM * HDIM / 256), 256, 0, stream>>>(H, Htr);

    for (int t = 0; t < 4; ++t) {
        if (dense)
            gemm1_dense_kernel<<<dim3(NPAD / 128, 4, KZ), 512, 0, stream>>>(At, hTt, agg);
        else
            gemm1_bits_kernel<<<dim3(NPAD / 128, 4, KZ), 512, 0, stream>>>(packedT, hTt, agg);
        gemm2_kernel<<<dim3(NROW / 8), 256, 0, stream>>>(agg, Htr, hf,
                                                         out + (size_t)t * NROW * HDIM, hTt);
    }
}

// Round 9
// 1067.201 us; speedup vs baseline: 1.1233x; 1.1233x over previous
//
#include <hip/hip_runtime.h>

#define NROW 5000
#define NPAD 5120   // padded rows
#define KW   80     // u64 words per padded row
#define KC   80     // 64-k chunks
#define KZ   4      // split-K
#define KCQ  20     // chunks per split
#define HDIM 128
#define MTI  4      // 32-row MFMA tiles per block (128 rows)
#define FXS  4194304.0f                  // 2^22 fixed-point scale
#define PART ((size_t)4 * NROW * HDIM)   // agg elements per kz part

typedef _Float16 f16x8 __attribute__((ext_vector_type(8)));
typedef float f32x16 __attribute__((ext_vector_type(16)));

__device__ __forceinline__ unsigned short f2h_int(int v) {   // exact for |v| <= 2048
    union { _Float16 h; unsigned short u; } c;
    c.h = (_Float16)(float)v;
    return c.u;
}
// q = round(h*2^22); digits base 2048: q == d1*2048 + d0
__device__ __forceinline__ void fx_digits(float h, unsigned short& d1, unsigned short& d0) {
    int q = (int)rintf(h * FXS);
    d1 = f2h_int(q >> 11);
    d0 = f2h_int(q & 2047);
}

// Fragment-major B layout: element (kc, pl, kk, half, col, j) holds digit plane pl of
// k = kc*64 + kk*16 + half*8 + j for column col. strides in f16 units: kc 16384,
// pl 8192, kk 2048, half 1024, col 8. One kc slab = 32 KB, contiguous.
__device__ __forceinline__ size_t bt_idx(int kc, int pl, int kk, int half, int col, int j) {
    return (((((size_t)kc * 2 + pl) * 4 + kk) * 2 + half) * 128 + col) * 8 + j;
}

// ---- prep: resolve atom indices; detect int32 vs int64 storage device-side ----
__global__ __launch_bounds__(256) void prep_atom_kernel(const unsigned int* __restrict__ atomw,
                                                        int* __restrict__ atomIdx) {
    __shared__ int s_is64;
    if (threadIdx.x == 0) {
        bool all0 = true, anynz = false;
        for (int j = 0; j < 64; ++j) {
            unsigned lo = atomw[2 * j], hi = atomw[2 * j + 1];
            all0 = all0 && (hi == 0u);
            anynz = anynz || (lo != 0u);
        }
        s_is64 = (all0 && anynz) ? 1 : 0;
    }
    __syncthreads();
    int v = blockIdx.x * 256 + threadIdx.x;
    if (v < NROW) atomIdx[v] = s_is64 ? (int)atomw[2 * v] : (int)atomw[v];
}

// ---- prep: bit-pack adjacency, ROW-major (one block per (e,row) = 20480 blocks, max MLP) ----
__global__ __launch_bounds__(256) void prep_pack_kernel(const int* __restrict__ adjs,
                                                        unsigned long long* __restrict__ packedR) {
    const int er = blockIdx.x;            // [0, 4*NPAD)
    const int e = er / NPAD;
    const int r = er - e * NPAD;
    const int wave = threadIdx.x >> 6;
    const int lane = threadIdx.x & 63;
    const int* rowp = adjs + ((size_t)e * NROW + r) * NROW;
    unsigned long long* outp = packedR + ((size_t)e * NPAD + r) * KW;
    const bool rok = (r < NROW);
    for (int c = wave; c < KW; c += 4) {
        int u = c * 64 + lane;
        int val = (rok && u < NROW) ? rowp[u] : 0;
        unsigned long long m = __ballot(val == 1);
        if (lane == 0) outp[c] = m;
    }
}

// ---- prep: transpose packed bits row-major -> kc-major via LDS (coalesced both sides) ----
__global__ __launch_bounds__(256) void prep_packT_kernel(const unsigned long long* __restrict__ packedR,
                                                         unsigned long long* __restrict__ packedT) {
    __shared__ unsigned long long slds[64][KW + 1];   // 41.5 KB, pad breaks bank alias
    const int e = blockIdx.y;
    const int r0 = blockIdx.x * 64;
    const int tid = threadIdx.x;
#pragma unroll
    for (int p = 0; p < 20; ++p) {        // 64 r x 80 c = 5120 words / 256 thr
        int idx = p * 256 + tid;
        int r = idx / KW;
        int c = idx - r * KW;
        slds[r][c] = packedR[((size_t)e * NPAD + r0 + r) * KW + c];
    }
    __syncthreads();
#pragma unroll
    for (int p = 0; p < 20; ++p) {
        int idx = p * 256 + tid;
        int kc = idx >> 6;
        int rr = idx & 63;
        packedT[((size_t)e * KC + kc) * NPAD + r0 + rr] = slds[rr][kc];
    }
}

// ------- prep: h0 -> fragment-major f16 digit planes from fp32 embedding -------
__global__ __launch_bounds__(256) void prep_h0T_kernel(const int* __restrict__ atomIdx,
                                                       const float* __restrict__ emb,
                                                       unsigned short* __restrict__ hTt) {
    const int i = blockIdx.y;
    const int v = blockIdx.x * 256 + threadIdx.x;   // < NPAD (k index)
    float val = 0.f;
    if (v < NROW) val = emb[(size_t)atomIdx[v] * HDIM + i];
    unsigned short d1, d0;
    fx_digits(val, d1, d0);
    const int kc = v >> 6, kk = (v >> 4) & 3, half = (v >> 3) & 1, j = v & 7;
    hTt[bt_idx(kc, 0, kk, half, i, j)] = d1;
    hTt[bt_idx(kc, 1, kk, half, i, j)] = d0;
}

// ---------------- prep: h0 fp32 row-major state ----------------
__global__ __launch_bounds__(256) void prep_h0f_kernel(const int* __restrict__ atomIdx,
                                                       const float* __restrict__ emb,
                                                       float* __restrict__ h) {
    int idx = blockIdx.x * 256 + threadIdx.x;   // < NROW*HDIM
    int v = idx >> 7, i = idx & 127;
    h[idx] = emb[(size_t)atomIdx[v] * HDIM + i];
}

// ---------------- prep: Htr[(e*128+j)*128 + i] = H[e][i][j] (fp32) ----------------
__global__ __launch_bounds__(256) void prep_Ht_kernel(const float* __restrict__ H,
                                                      float* __restrict__ Htr) {
    int idx = blockIdx.x * 256 + threadIdx.x;   // < 4*128*128
    int e = idx >> 14;
    int j = (idx >> 7) & 127;
    int i = idx & 127;
    Htr[idx] = H[((size_t)e * HDIM + i) * HDIM + j];
}

// ---- GEMM1 v4 (EXACT, LDS-staged B, 32x32x16 MFMA): agg = A * h ----
// Block 256 thr = 4 waves (col split 4x32); block tile 128r x 128c; MTI=4.
// B slab per kc = 32 KB contiguous -> double-buffered LDS via global_load_lds(16B),
// stage(kc+1) issued before compute(kc), one barrier per kc drains (T3-minimum).
// Converts the per-wave 8x global-B-load latency chain (L3/cross-XCD, ~600-900 cyc,
// re-paid every kc) into ds_read_b128 (~12 cyc) + overlapped staging.
// MFMA sequence and operand values identical to round-5 kernel -> bit-exact.
__global__ __launch_bounds__(256, 2) void gemm1_kernel(const unsigned long long* __restrict__ packedT,
                                                       const unsigned short* __restrict__ hTt,
                                                       float* __restrict__ agg) {
    __shared__ _Float16 Bs[2][16384];    // 2 x 32 KB double buffer
    const int m0 = blockIdx.x * 128;
    const int e = blockIdx.y;
    const int kz = blockIdx.z;
    const int tid = threadIdx.x;
    const int lane = tid & 63;
    const int wave = tid >> 6;
    const int l31 = lane & 31;
    const int l1 = lane >> 5;            // half-wave selector
    const int sh2 = l1 * 8;              // bit offset within 16-bit k-group
    const int col = wave * 32 + l31;
    const int kc0 = kz * KCQ;

    f32x16 acc[2][MTI];                  // [pl][mt]
#pragma unroll
    for (int pl = 0; pl < 2; ++pl)
#pragma unroll
        for (int mt = 0; mt < MTI; ++mt) acc[pl][mt] = (f32x16)(0.f);

    const unsigned long long* ap = packedT + ((size_t)e * KC + kc0) * NPAD + m0 + l31;
    const char* bslab = (const char*)hTt + (size_t)kc0 * 32768;   // this kz's B slabs

    // stage one 32 KB slab: 8 x (256 thr x 16 B); LDS dest = wave-uniform base + lane*16
#define STAGE(BUF, KCV)                                                         \
    {                                                                           \
        const char* gs_ = bslab + (size_t)(KCV) * 32768;                        \
        char* ls_ = (char*)&Bs[BUF][0] + (tid & 192) * 16;                      \
        _Pragma("unroll") for (int c_ = 0; c_ < 8; ++c_)                        \
            __builtin_amdgcn_global_load_lds(                                   \
                (const unsigned int*)(gs_ + c_ * 4096 + tid * 16),              \
                (unsigned int*)(ls_ + c_ * 4096), 16, 0, 0);                    \
    }

    STAGE(0, 0)
    __syncthreads();                     // drains buf0 staging (compiler emits vmcnt(0))

    int cur = 0;
    for (int kc = 0; kc < KCQ; ++kc) {
        unsigned long long aw[MTI];
#pragma unroll
        for (int mt = 0; mt < MTI; ++mt) aw[mt] = ap[mt * 32];
        ap += NPAD;

        if (kc + 1 < KCQ) STAGE(cur ^ 1, kc + 1)   // overlaps with compute below

        const _Float16* bl = &Bs[cur][(size_t)l1 * 1024 + col * 8];
        f16x8 bf[2][4];                  // [pl][kk] from LDS (ds_read_b128)
#pragma unroll
        for (int pl = 0; pl < 2; ++pl)
#pragma unroll
            for (int kk = 0; kk < 4; ++kk)
                bf[pl][kk] = *(const f16x8*)(bl + (pl * 4 + kk) * 2048);

#pragma unroll
        for (int kk = 0; kk < 4; ++kk) {
#pragma unroll
            for (int mt = 0; mt < MTI; ++mt) {
                unsigned int w = (kk < 2) ? (unsigned int)aw[mt]
                                          : (unsigned int)(aw[mt] >> 32);
                unsigned int b = (w >> ((kk & 1) * 16 + sh2)) & 0xFFu;
                unsigned int y = b | (b << 15);
                union { unsigned int u[4]; f16x8 h; } Af;
#pragma unroll
                for (int q = 0; q < 4; ++q)
                    Af.u[q] = ((y >> (2 * q)) & 0x00010001u) * 0x3C00u;  // bit pair -> f16 {0,1}
#pragma unroll
                for (int pl = 0; pl < 2; ++pl)
                    acc[pl][mt] = __builtin_amdgcn_mfma_f32_32x32x16_f16(
                        Af.h, bf[pl][kk], acc[pl][mt], 0, 0, 0);
            }
        }
        __syncthreads();                 // drains next-slab staging; guards buffer reuse
        cur ^= 1;
    }
#undef STAGE

    // epilogue: exact digit combine in double, one optimal fp32 rounding
    float* aggz = agg + (size_t)kz * PART;
#pragma unroll
    for (int mt = 0; mt < MTI; ++mt)
#pragma unroll
        for (int reg = 0; reg < 16; ++reg) {
            int row = (reg & 3) + 8 * (reg >> 2) + 4 * l1;
            int v = m0 + mt * 32 + row;
            if (v < NROW) {
                double d = (double)acc[0][mt][reg] * 2048.0 + (double)acc[1][mt][reg];
                aggz[((size_t)e * NROW + v) * HDIM + col] = (float)(d * (1.0 / 4194304.0));
            }
        }
}

// --- GEMM2: msg[v][i] = sum_ej Htr[ej][i]*agg[v][ej], sigmoid, fp32 out + digits ---
// 8-row tiles, 625 blocks; 2x2 register blocking; c-loop unrolled 4x for 16-deep
// Htr load MLP (accumulation order per m[r][q][k] unchanged -> bit-exact).
__global__ __launch_bounds__(256) void gemm2_kernel(const float* __restrict__ agg,
                                                    const float* __restrict__ Htr,
                                                    float* __restrict__ hf,       // fp32 state, in/out
                                                    float* __restrict__ outp,     // d_out slice t (fp32)
                                                    unsigned short* __restrict__ hTt) {
    __shared__ float aggs[8][512];             // 16 KB
    __shared__ unsigned short hs[2][128][8];   // 4 KB digit transpose buffers
    const int tid = threadIdx.x;
    const int v0 = blockIdx.x * 8;             // < 5000 always (625*8 = 5000)

    // stage 8 rows x 512 (sum of 4 kz parts), float4
#pragma unroll
    for (int it = 0; it < 4; ++it) {
        int idx = it * 256 + tid;          // float4 index, 0..1023
        int r = idx >> 7;
        int c = (idx & 127) * 4;
        int e = c >> 7, j = c & 127;
        size_t o = ((size_t)e * NROW + (v0 + r)) * HDIM + j;
        float4 a0 = *(const float4*)&agg[o];
        float4 a1 = *(const float4*)&agg[PART + o];
        float4 a2 = *(const float4*)&agg[2 * PART + o];
        float4 a3 = *(const float4*)&agg[3 * PART + o];
        *(float4*)&aggs[r][c] = make_float4((a0.x + a1.x) + (a2.x + a3.x),
                                            (a0.y + a1.y) + (a2.y + a3.y),
                                            (a0.z + a1.z) + (a2.z + a3.z),
                                            (a0.w + a1.w) + (a2.w + a3.w));
    }
    __syncthreads();

    const int ip = tid & 63;
    const int vg = tid >> 6;             // 0..3 -> rows vg*2, vg*2+1
    const int i0 = ip * 2;

    float m[2][2][4];                    // [row][i-col][k-lane]
#pragma unroll
    for (int r = 0; r < 2; ++r)
#pragma unroll
        for (int q = 0; q < 2; ++q)
#pragma unroll
            for (int k = 0; k < 4; ++k) m[r][q][k] = 0.f;

    const int rb = vg * 2;
#pragma unroll 4
    for (int cg = 0; cg < 128; ++cg) {
        int c = cg * 4;
        float4 q0 = *(const float4*)&aggs[rb][c];       // broadcast, conflict-free
        float4 q1 = *(const float4*)&aggs[rb + 1][c];
        float a0v[4] = {q0.x, q0.y, q0.z, q0.w};
        float a1v[4] = {q1.x, q1.y, q1.z, q1.w};
#pragma unroll
        for (int k = 0; k < 4; ++k) {
            float2 w = *(const float2*)&Htr[(size_t)(c + k) * HDIM + i0];
            m[0][0][k] += a0v[k] * w.x;
            m[0][1][k] += a0v[k] * w.y;
            m[1][0][k] += a1v[k] * w.x;
            m[1][1][k] += a1v[k] * w.y;
        }
    }

#pragma unroll
    for (int r = 0; r < 2; ++r) {
        int vr = rb + r;
        int v = v0 + vr;
        size_t o = (size_t)v * HDIM + i0;
        float2 hv = *(const float2*)&hf[o];
        float ms0 = (m[r][0][0] + m[r][0][1]) + (m[r][0][2] + m[r][0][3]);
        float ms1 = (m[r][1][0] + m[r][1][1]) + (m[r][1][2] + m[r][1][3]);
        float x0 = hv.x + ms0;
        float x1 = hv.y + ms1;
        float s0 = 1.0f / (1.0f + expf(-x0));
        float s1 = 1.0f / (1.0f + expf(-x1));
        *(float2*)&outp[o] = make_float2(s0, s1);
        *(float2*)&hf[o] = make_float2(s0, s1);
        unsigned short d1a, d0a, d1b, d0b;
        fx_digits(s0, d1a, d0a);
        fx_digits(s1, d1b, d0b);
        hs[0][i0][vr] = d1a;
        hs[1][i0][vr] = d0a;
        hs[0][i0 + 1][vr] = d1b;
        hs[1][i0 + 1][vr] = d0b;
    }
    __syncthreads();
    if (tid < 128) {    // one uint4 (8 k-entries) per plane, coalesced
        const int kc = v0 >> 6, kk = (v0 >> 4) & 3, half = (v0 >> 3) & 1;
#pragma unroll
        for (int pl = 0; pl < 2; ++pl)
            *(uint4*)&hTt[bt_idx(kc, pl, kk, half, tid, 0)] = *(const uint4*)&hs[pl][tid][0];
    }
}

extern "C" void kernel_launch(void* const* d_in, const int* in_sizes, int n_in,
                              void* d_out, int out_size, void* d_ws, size_t ws_size,
                              hipStream_t stream) {
    const unsigned int* atomw = (const unsigned int*)d_in[0];  // int32 OR int64 — sniffed on device
    const int* adjs = (const int*)d_in[1];                     // int32
    // d_in[2] = max_time_steps; reference constant T=4 hard-coded
    const float* emb = (const float*)d_in[3];                  // fp32
    const float* H = (const float*)d_in[4];                    // fp32
    float* out = (float*)d_out;                                // fp32 output

    char* ws = (char*)d_ws;
    unsigned long long* packedT = (unsigned long long*)ws;           // 13,107,200 B (kc-major)
    size_t off = (size_t)4 * KC * NPAD * 8;
    unsigned short* hTt = (unsigned short*)(ws + off);               // 2 planes fragment-major
    off += (size_t)2 * KC * HDIM * 64 * 2;
    float* hf = (float*)(ws + off);                                  // 2,560,000 B
    off += (size_t)NROW * HDIM * 4;
    float* agg = (float*)(ws + off);                                 // 4 parts = 40,960,000 B
    off += (size_t)KZ * PART * 4;
    float* Htr = (float*)(ws + off);                                 // 262,144 B
    off += (size_t)4 * HDIM * HDIM * 4;
    int* atomIdx = (int*)(ws + off);                                 // 20,000 B
    off += (size_t)NROW * 4;
    off = (off + 255) & ~(size_t)255;
    unsigned long long* packedR = (unsigned long long*)(ws + off);   // 13,107,200 B (row-major)
    off += (size_t)4 * NPAD * KW * 8;

    prep_atom_kernel<<<dim3((NROW + 255) / 256), 256, 0, stream>>>(atomw, atomIdx);
    prep_pack_kernel<<<dim3(4 * NPAD), 256, 0, stream>>>(adjs, packedR);
    prep_packT_kernel<<<dim3(NPAD / 64, 4), 256, 0, stream>>>(packedR, packedT);
    prep_h0T_kernel<<<dim3(NPAD / 256, HDIM), 256, 0, stream>>>(atomIdx, emb, hTt);
    prep_h0f_kernel<<<dim3(NROW * HDIM / 256), 256, 0, stream>>>(atomIdx, emb, hf);
    prep_Ht_kernel<<<dim3(4 * HDIM * HDIM / 256), 256, 0, stream>>>(H, Htr);

    for (int t = 0; t < 4; ++t) {
        gemm1_kernel<<<dim3(NPAD / 128, 4, KZ), 256, 0, stream>>>(packedT, hTt, agg);
        gemm2_kernel<<<dim3(NROW / 8), 256, 0, stream>>>(agg, Htr, hf,
                                                         out + (size_t)t * NROW * HDIM, hTt);
    }
}

// Round 10
// 958.027 us; speedup vs baseline: 1.2513x; 1.1140x over previous
//
#include <hip/hip_runtime.h>

#define NROW 5000
#define NPAD 5120   // padded rows
#define KW   80     // u64 words per padded row
#define KC   80     // 64-k chunks
#define KZ   4      // split-K
#define KCQ  20     // chunks per split
#define HDIM 128
#define MTI  4      // 32-row MFMA tiles per block (128 rows)
#define FXS  4194304.0f                  // 2^22 fixed-point scale
#define PART ((size_t)4 * NROW * HDIM)   // agg elements per kz part

typedef _Float16 f16x8 __attribute__((ext_vector_type(8)));
typedef float f32x16 __attribute__((ext_vector_type(16)));

__device__ __forceinline__ unsigned short f2h_int(int v) {   // exact for |v| <= 2048
    union { _Float16 h; unsigned short u; } c;
    c.h = (_Float16)(float)v;
    return c.u;
}
// q = round(h*2^22); digits base 2048: q == d1*2048 + d0
__device__ __forceinline__ void fx_digits(float h, unsigned short& d1, unsigned short& d0) {
    int q = (int)rintf(h * FXS);
    d1 = f2h_int(q >> 11);
    d0 = f2h_int(q & 2047);
}

// Fragment-major B layout: element (kc, pl, kk, half, col, j) holds digit plane pl of
// k = kc*64 + kk*16 + half*8 + j for column col. strides in f16 units: kc 16384,
// pl 8192, kk 2048, half 1024, col 8.
__device__ __forceinline__ size_t bt_idx(int kc, int pl, int kk, int half, int col, int j) {
    return (((((size_t)kc * 2 + pl) * 4 + kk) * 2 + half) * 128 + col) * 8 + j;
}

// ---- prep: resolve atom indices; detect int32 vs int64 storage device-side ----
__global__ __launch_bounds__(256) void prep_atom_kernel(const unsigned int* __restrict__ atomw,
                                                        int* __restrict__ atomIdx) {
    __shared__ int s_is64;
    if (threadIdx.x == 0) {
        bool all0 = true, anynz = false;
        for (int j = 0; j < 64; ++j) {
            unsigned lo = atomw[2 * j], hi = atomw[2 * j + 1];
            all0 = all0 && (hi == 0u);
            anynz = anynz || (lo != 0u);
        }
        s_is64 = (all0 && anynz) ? 1 : 0;
    }
    __syncthreads();
    int v = blockIdx.x * 256 + threadIdx.x;
    if (v < NROW) atomIdx[v] = s_is64 ? (int)atomw[2 * v] : (int)atomw[v];
}

// ---- prep: bit-pack adjacency, ROW-major (one block per (e,row) = 20480 blocks, max MLP) ----
__global__ __launch_bounds__(256) void prep_pack_kernel(const int* __restrict__ adjs,
                                                        unsigned long long* __restrict__ packedR) {
    const int er = blockIdx.x;            // [0, 4*NPAD)
    const int e = er / NPAD;
    const int r = er - e * NPAD;
    const int wave = threadIdx.x >> 6;
    const int lane = threadIdx.x & 63;
    const int* rowp = adjs + ((size_t)e * NROW + r) * NROW;
    unsigned long long* outp = packedR + ((size_t)e * NPAD + r) * KW;
    const bool rok = (r < NROW);
    for (int c = wave; c < KW; c += 4) {
        int u = c * 64 + lane;
        int val = (rok && u < NROW) ? rowp[u] : 0;
        unsigned long long m = __ballot(val == 1);
        if (lane == 0) outp[c] = m;
    }
}

// ---- prep: transpose packed bits row-major -> kc-major via LDS (coalesced both sides) ----
__global__ __launch_bounds__(256) void prep_packT_kernel(const unsigned long long* __restrict__ packedR,
                                                         unsigned long long* __restrict__ packedT) {
    __shared__ unsigned long long slds[64][KW + 1];   // 41.5 KB, pad breaks bank alias
    const int e = blockIdx.y;
    const int r0 = blockIdx.x * 64;
    const int tid = threadIdx.x;
#pragma unroll
    for (int p = 0; p < 20; ++p) {        // 64 r x 80 c = 5120 words / 256 thr
        int idx = p * 256 + tid;
        int r = idx / KW;
        int c = idx - r * KW;
        slds[r][c] = packedR[((size_t)e * NPAD + r0 + r) * KW + c];
    }
    __syncthreads();
#pragma unroll
    for (int p = 0; p < 20; ++p) {
        int idx = p * 256 + tid;
        int kc = idx >> 6;
        int rr = idx & 63;
        packedT[((size_t)e * KC + kc) * NPAD + r0 + rr] = slds[rr][kc];
    }
}

// ------- prep: h0 -> fragment-major f16 digit planes from fp32 embedding -------
__global__ __launch_bounds__(256) void prep_h0T_kernel(const int* __restrict__ atomIdx,
                                                       const float* __restrict__ emb,
                                                       unsigned short* __restrict__ hTt) {
    const int i = blockIdx.y;
    const int v = blockIdx.x * 256 + threadIdx.x;   // < NPAD (k index)
    float val = 0.f;
    if (v < NROW) val = emb[(size_t)atomIdx[v] * HDIM + i];
    unsigned short d1, d0;
    fx_digits(val, d1, d0);
    const int kc = v >> 6, kk = (v >> 4) & 3, half = (v >> 3) & 1, j = v & 7;
    hTt[bt_idx(kc, 0, kk, half, i, j)] = d1;
    hTt[bt_idx(kc, 1, kk, half, i, j)] = d0;
}

// ---------------- prep: h0 fp32 row-major state ----------------
__global__ __launch_bounds__(256) void prep_h0f_kernel(const int* __restrict__ atomIdx,
                                                       const float* __restrict__ emb,
                                                       float* __restrict__ h) {
    int idx = blockIdx.x * 256 + threadIdx.x;   // < NROW*HDIM
    int v = idx >> 7, i = idx & 127;
    h[idx] = emb[(size_t)atomIdx[v] * HDIM + i];
}

// ---------------- prep: Htr[(e*128+j)*128 + i] = H[e][i][j] (fp32) ----------------
__global__ __launch_bounds__(256) void prep_Ht_kernel(const float* __restrict__ H,
                                                      float* __restrict__ Htr) {
    int idx = blockIdx.x * 256 + threadIdx.x;   // < 4*128*128
    int e = idx >> 14;
    int j = (idx >> 7) & 127;
    int i = idx & 127;
    Htr[idx] = H[((size_t)e * HDIM + i) * HDIM + j];
}

// ---- GEMM1 (EXACT, barrier-free, LDS-free, 32x32x16 MFMA): agg = A * h ----
// Round-5 structure (best measured; 5 structural variants all ~equal). Expansion uses
// (t<<14)-(t<<10) == t*0x3C00 (full-rate shifts/sub instead of possibly quarter-rate mul).
// A frag: row=lane&31, k=(lane>>5)*8+j. C/D: col=lane&31, row=(reg&3)+8*(reg>>2)+4*(lane>>5).
__global__ __launch_bounds__(256, 2) void gemm1_kernel(const unsigned long long* __restrict__ packedT,
                                                       const unsigned short* __restrict__ hTt,
                                                       float* __restrict__ agg) {
    const int m0 = blockIdx.x * 128;
    const int e = blockIdx.y;
    const int kz = blockIdx.z;
    const int tid = threadIdx.x;
    const int lane = tid & 63;
    const int wave = tid >> 6;
    const int l31 = lane & 31;
    const int l1 = lane >> 5;            // half-wave selector
    const int sh2 = l1 * 8;              // bit offset within 16-bit k-group
    const int col = wave * 32 + l31;
    const int kc0 = kz * KCQ;

    f32x16 acc[2][MTI];                  // [pl][mt] = 128 regs
#pragma unroll
    for (int pl = 0; pl < 2; ++pl)
#pragma unroll
        for (int mt = 0; mt < MTI; ++mt) acc[pl][mt] = (f32x16)(0.f);

    const unsigned long long* ap = packedT + ((size_t)e * KC + kc0) * NPAD + m0 + l31;
    const _Float16* bp = (const _Float16*)hTt + (size_t)kc0 * 16384 +
                         (size_t)l1 * 1024 + (size_t)col * 8;

    for (int kc = 0; kc < KCQ; ++kc) {
        unsigned long long aw[MTI];
#pragma unroll
        for (int mt = 0; mt < MTI; ++mt) aw[mt] = ap[mt * 32];

        f16x8 bf[2][4];                  // [pl][kk]
#pragma unroll
        for (int pl = 0; pl < 2; ++pl)
#pragma unroll
            for (int kk = 0; kk < 4; ++kk)
                bf[pl][kk] = *(const f16x8*)(bp + pl * 8192 + kk * 2048);

        ap += NPAD;
        bp += 16384;

#pragma unroll
        for (int kk = 0; kk < 4; ++kk) {
#pragma unroll
            for (int mt = 0; mt < MTI; ++mt) {
                unsigned int w = (kk < 2) ? (unsigned int)aw[mt]
                                          : (unsigned int)(aw[mt] >> 32);
                unsigned int b = (w >> ((kk & 1) * 16 + sh2)) & 0xFFu;
                unsigned int y = b | (b << 15);
                union { unsigned int u[4]; f16x8 h; } Af;
#pragma unroll
                for (int q = 0; q < 4; ++q) {
                    unsigned int t = (y >> (2 * q)) & 0x00010001u;
                    Af.u[q] = (t << 14) - (t << 10);   // == t*0x3C00: bit pair -> f16 {0,1}
                }
#pragma unroll
                for (int pl = 0; pl < 2; ++pl)
                    acc[pl][mt] = __builtin_amdgcn_mfma_f32_32x32x16_f16(
                        Af.h, bf[pl][kk], acc[pl][mt], 0, 0, 0);
            }
        }
    }

    // epilogue: exact digit combine in double, one optimal fp32 rounding
    float* aggz = agg + (size_t)kz * PART;
#pragma unroll
    for (int mt = 0; mt < MTI; ++mt)
#pragma unroll
        for (int reg = 0; reg < 16; ++reg) {
            int row = (reg & 3) + 8 * (reg >> 2) + 4 * l1;
            int v = m0 + mt * 32 + row;
            if (v < NROW) {
                double d = (double)acc[0][mt][reg] * 2048.0 + (double)acc[1][mt][reg];
                aggz[((size_t)e * NROW + v) * HDIM + col] = (float)(d * (1.0 / 4194304.0));
            }
        }
}

// --- GEMM2 v2: msg[v][i] = sum_ej Htr[ej][i]*agg[v][ej], sigmoid, fp32 out + digits ---
// 8-row tiles, 625 blocks. Htr staged through LDS in 32 KB chunks (64 c x 128 i):
// kills the 4x inter-warp redundancy (655 -> ~160 MB L2 traffic/launch) and moves the
// hot-loop weight reads to conflict-free ds_read_b64. Accumulation sequence (c ascending,
// k inner, m[r][q][k] partials, same final combines) identical -> bit-exact.
// LDS 52 KB -> 3 blocks/CU; 625 blocks = one residency round.
__global__ __launch_bounds__(256) void gemm2_kernel(const float* __restrict__ agg,
                                                    const float* __restrict__ Htr,
                                                    float* __restrict__ hf,       // fp32 state, in/out
                                                    float* __restrict__ outp,     // d_out slice t (fp32)
                                                    unsigned short* __restrict__ hTt) {
    __shared__ float aggs[8][512];             // 16 KB
    __shared__ float hw[64][128];              // 32 KB Htr chunk
    __shared__ unsigned short hs[2][128][8];   // 4 KB digit transpose buffers
    const int tid = threadIdx.x;
    const int v0 = blockIdx.x * 8;             // < 5000 always (625*8 = 5000)

    // stage 8 rows x 512 (sum of 4 kz parts), float4
#pragma unroll
    for (int it = 0; it < 4; ++it) {
        int idx = it * 256 + tid;          // float4 index, 0..1023
        int r = idx >> 7;
        int c = (idx & 127) * 4;
        int e = c >> 7, j = c & 127;
        size_t o = ((size_t)e * NROW + (v0 + r)) * HDIM + j;
        float4 a0 = *(const float4*)&agg[o];
        float4 a1 = *(const float4*)&agg[PART + o];
        float4 a2 = *(const float4*)&agg[2 * PART + o];
        float4 a3 = *(const float4*)&agg[3 * PART + o];
        *(float4*)&aggs[r][c] = make_float4((a0.x + a1.x) + (a2.x + a3.x),
                                            (a0.y + a1.y) + (a2.y + a3.y),
                                            (a0.z + a1.z) + (a2.z + a3.z),
                                            (a0.w + a1.w) + (a2.w + a3.w));
    }
    __syncthreads();

    const int ip = tid & 63;
    const int vg = tid >> 6;             // 0..3 -> rows vg*2, vg*2+1
    const int i0 = ip * 2;
    const int rb = vg * 2;

    float m[2][2][4];                    // [row][i-col][k-lane]
#pragma unroll
    for (int r = 0; r < 2; ++r)
#pragma unroll
        for (int q = 0; q < 2; ++q)
#pragma unroll
            for (int k = 0; k < 4; ++k) m[r][q][k] = 0.f;

    for (int c0 = 0; c0 < 512; c0 += 64) {
        // stage Htr[c0..c0+63][0..127] -> 8192 floats, 256 thr x 8 float4 (coalesced)
#pragma unroll
        for (int p = 0; p < 8; ++p) {
            int idx = p * 256 + tid;           // float4 index, 0..2047
            int cc = idx >> 5;                 // 0..63
            int i4 = (idx & 31) * 4;           // 0..124
            *(float4*)&hw[cc][i4] = *(const float4*)&Htr[(size_t)(c0 + cc) * HDIM + i4];
        }
        __syncthreads();

#pragma unroll 4
        for (int cg = 0; cg < 16; ++cg) {
            int cl = cg * 4;
            float4 q0 = *(const float4*)&aggs[rb][c0 + cl];       // broadcast, conflict-free
            float4 q1 = *(const float4*)&aggs[rb + 1][c0 + cl];
            float a0v[4] = {q0.x, q0.y, q0.z, q0.w};
            float a1v[4] = {q1.x, q1.y, q1.z, q1.w};
#pragma unroll
            for (int k = 0; k < 4; ++k) {
                float2 w = *(const float2*)&hw[cl + k][i0];       // 2-way bank alias = free
                m[0][0][k] += a0v[k] * w.x;
                m[0][1][k] += a0v[k] * w.y;
                m[1][0][k] += a1v[k] * w.x;
                m[1][1][k] += a1v[k] * w.y;
            }
        }
        __syncthreads();                       // protect hw overwrite next chunk
    }

#pragma unroll
    for (int r = 0; r < 2; ++r) {
        int vr = rb + r;
        int v = v0 + vr;
        size_t o = (size_t)v * HDIM + i0;
        float2 hv = *(const float2*)&hf[o];
        float ms0 = (m[r][0][0] + m[r][0][1]) + (m[r][0][2] + m[r][0][3]);
        float ms1 = (m[r][1][0] + m[r][1][1]) + (m[r][1][2] + m[r][1][3]);
        float x0 = hv.x + ms0;
        float x1 = hv.y + ms1;
        float s0 = 1.0f / (1.0f + expf(-x0));
        float s1 = 1.0f / (1.0f + expf(-x1));
        *(float2*)&outp[o] = make_float2(s0, s1);
        *(float2*)&hf[o] = make_float2(s0, s1);
        unsigned short d1a, d0a, d1b, d0b;
        fx_digits(s0, d1a, d0a);
        fx_digits(s1, d1b, d0b);
        hs[0][i0][vr] = d1a;
        hs[1][i0][vr] = d0a;
        hs[0][i0 + 1][vr] = d1b;
        hs[1][i0 + 1][vr] = d0b;
    }
    __syncthreads();
    if (tid < 128) {    // one uint4 (8 k-entries) per plane, coalesced
        const int kc = v0 >> 6, kk = (v0 >> 4) & 3, half = (v0 >> 3) & 1;
#pragma unroll
        for (int pl = 0; pl < 2; ++pl)
            *(uint4*)&hTt[bt_idx(kc, pl, kk, half, tid, 0)] = *(const uint4*)&hs[pl][tid][0];
    }
}

extern "C" void kernel_launch(void* const* d_in, const int* in_sizes, int n_in,
                              void* d_out, int out_size, void* d_ws, size_t ws_size,
                              hipStream_t stream) {
    const unsigned int* atomw = (const unsigned int*)d_in[0];  // int32 OR int64 — sniffed on device
    const int* adjs = (const int*)d_in[1];                     // int32
    // d_in[2] = max_time_steps; reference constant T=4 hard-coded
    const float* emb = (const float*)d_in[3];                  // fp32
    const float* H = (const float*)d_in[4];                    // fp32
    float* out = (float*)d_out;                                // fp32 output

    char* ws = (char*)d_ws;
    unsigned long long* packedT = (unsigned long long*)ws;           // 13,107,200 B (kc-major)
    size_t off = (size_t)4 * KC * NPAD * 8;
    unsigned short* hTt = (unsigned short*)(ws + off);               // 2 planes fragment-major
    off += (size_t)2 * KC * HDIM * 64 * 2;
    float* hf = (float*)(ws + off);                                  // 2,560,000 B
    off += (size_t)NROW * HDIM * 4;
    float* agg = (float*)(ws + off);                                 // 4 parts = 40,960,000 B
    off += (size_t)KZ * PART * 4;
    float* Htr = (float*)(ws + off);                                 // 262,144 B
    off += (size_t)4 * HDIM * HDIM * 4;
    int* atomIdx = (int*)(ws + off);                                 // 20,000 B
    off += (size_t)NROW * 4;
    off = (off + 255) & ~(size_t)255;
    unsigned long long* packedR = (unsigned long long*)(ws + off);   // 13,107,200 B (row-major)
    off += (size_t)4 * NPAD * KW * 8;

    prep_atom_kernel<<<dim3((NROW + 255) / 256), 256, 0, stream>>>(atomw, atomIdx);
    prep_pack_kernel<<<dim3(4 * NPAD), 256, 0, stream>>>(adjs, packedR);
    prep_packT_kernel<<<dim3(NPAD / 64, 4), 256, 0, stream>>>(packedR, packedT);
    prep_h0T_kernel<<<dim3(NPAD / 256, HDIM), 256, 0, stream>>>(atomIdx, emb, hTt);
    prep_h0f_kernel<<<dim3(NROW * HDIM / 256), 256, 0, stream>>>(atomIdx, emb, hf);
    prep_Ht_kernel<<<dim3(4 * HDIM * HDIM / 256), 256, 0, stream>>>(H, Htr);

    for (int t = 0; t < 4; ++t) {
        gemm1_kernel<<<dim3(NPAD / 128, 4, KZ), 256, 0, stream>>>(packedT, hTt, agg);
        gemm2_kernel<<<dim3(NROW / 8), 256, 0, stream>>>(agg, Htr, hf,
                                                         out + (size_t)t * NROW * HDIM, hTt);
    }
}

// Round 11
// 945.698 us; speedup vs baseline: 1.2676x; 1.0130x over previous
//
#include <hip/hip_runtime.h>

#define NROW 5000
#define NPAD 5120   // padded rows
#define KW   80     // u64 words per padded row
#define KC   80     // 64-k chunks
#define KZ   4      // split-K
#define KCQ  20     // chunks per split
#define HDIM 128
#define MTI  4      // 32-row MFMA tiles per block (128 rows)
#define FXS  4194304.0f                  // 2^22 fixed-point scale
#define PART ((size_t)4 * NROW * HDIM)   // agg elements per kz part
#define H0T_BLKS (NPAD / 256 * HDIM)     // 2560
#define H0F_BLKS (NROW * HDIM / 256)     // 2500
#define HT_BLKS  (4 * HDIM * HDIM / 256) // 256

typedef _Float16 f16x8 __attribute__((ext_vector_type(8)));
typedef float f32x16 __attribute__((ext_vector_type(16)));

__device__ __forceinline__ unsigned short f2h_int(int v) {   // exact for |v| <= 2048
    union { _Float16 h; unsigned short u; } c;
    c.h = (_Float16)(float)v;
    return c.u;
}
// q = round(h*2^22); digits base 2048: q == d1*2048 + d0
__device__ __forceinline__ void fx_digits(float h, unsigned short& d1, unsigned short& d0) {
    int q = (int)rintf(h * FXS);
    d1 = f2h_int(q >> 11);
    d0 = f2h_int(q & 2047);
}

// Fragment-major B layout: element (kc, pl, kk, half, col, j) holds digit plane pl of
// k = kc*64 + kk*16 + half*8 + j for column col. strides in f16 units: kc 16384,
// pl 8192, kk 2048, half 1024, col 8.
__device__ __forceinline__ size_t bt_idx(int kc, int pl, int kk, int half, int col, int j) {
    return (((((size_t)kc * 2 + pl) * 4 + kk) * 2 + half) * 128 + col) * 8 + j;
}

// ---- prep: bit-pack adjacency, ROW-major (one block per (e,row) = 20480 blocks, max MLP) ----
__global__ __launch_bounds__(256) void prep_pack_kernel(const int* __restrict__ adjs,
                                                        unsigned long long* __restrict__ packedR) {
    const int er = blockIdx.x;            // [0, 4*NPAD)
    const int e = er / NPAD;
    const int r = er - e * NPAD;
    const int wave = threadIdx.x >> 6;
    const int lane = threadIdx.x & 63;
    const int* rowp = adjs + ((size_t)e * NROW + r) * NROW;
    unsigned long long* outp = packedR + ((size_t)e * NPAD + r) * KW;
    const bool rok = (r < NROW);
    for (int c = wave; c < KW; c += 4) {
        int u = c * 64 + lane;
        int val = (rok && u < NROW) ? rowp[u] : 0;
        unsigned long long m = __ballot(val == 1);
        if (lane == 0) outp[c] = m;
    }
}

// ---- prep: transpose packed bits row-major -> kc-major via LDS (coalesced both sides) ----
__global__ __launch_bounds__(256) void prep_packT_kernel(const unsigned long long* __restrict__ packedR,
                                                         unsigned long long* __restrict__ packedT) {
    __shared__ unsigned long long slds[64][KW + 1];   // 41.5 KB, pad breaks bank alias
    const int e = blockIdx.y;
    const int r0 = blockIdx.x * 64;
    const int tid = threadIdx.x;
#pragma unroll
    for (int p = 0; p < 20; ++p) {        // 64 r x 80 c = 5120 words / 256 thr
        int idx = p * 256 + tid;
        int r = idx / KW;
        int c = idx - r * KW;
        slds[r][c] = packedR[((size_t)e * NPAD + r0 + r) * KW + c];
    }
    __syncthreads();
#pragma unroll
    for (int p = 0; p < 20; ++p) {
        int idx = p * 256 + tid;
        int kc = idx >> 6;
        int rr = idx & 63;
        packedT[((size_t)e * KC + kc) * NPAD + r0 + rr] = slds[rr][kc];
    }
}

// ---- prep (merged): h0 digit planes + h0 fp32 state + Htr transpose, one dispatch ----
// blockIdx ranges: [0, 2560) h0T; [2560, 5060) h0f; [5060, 5316) Ht.
// int32/int64 atom storage sniffed per-block in parallel (128 L2-hit reads + shared ballot).
__global__ __launch_bounds__(256) void prep_misc_kernel(const unsigned int* __restrict__ atomw,
                                                        const float* __restrict__ emb,
                                                        const float* __restrict__ H,
                                                        unsigned short* __restrict__ hTt,
                                                        float* __restrict__ hf,
                                                        float* __restrict__ Htr) {
    const int b = blockIdx.x;
    const int tid = threadIdx.x;
    if (b >= H0T_BLKS + H0F_BLKS) {      // ---- Ht: Htr[(e*128+j)*128+i] = H[e][i][j] ----
        int idx = (b - H0T_BLKS - H0F_BLKS) * 256 + tid;
        int e = idx >> 14;
        int j = (idx >> 7) & 127;
        int i = idx & 127;
        Htr[idx] = H[((size_t)e * HDIM + i) * HDIM + j];
        return;
    }
    // is64 sniff: first 64 index-pairs; int64 iff all hi-words zero and some lo nonzero
    __shared__ int s_hi, s_lo;
    if (tid == 0) { s_hi = 0; s_lo = 0; }
    __syncthreads();
    if (tid < 128) {
        unsigned wv = atomw[tid];
        if (wv) {
            if (tid & 1) atomicOr(&s_hi, 1);
            else         atomicOr(&s_lo, 1);
        }
    }
    __syncthreads();
    const int is64 = (s_hi == 0 && s_lo != 0) ? 1 : 0;

    if (b < H0T_BLKS) {                  // ---- h0T: fragment-major f16 digit planes ----
        const int x = b % (NPAD / 256);
        const int i = b / (NPAD / 256);
        const int v = x * 256 + tid;     // k index < NPAD
        float val = 0.f;
        if (v < NROW) {
            int ai = is64 ? (int)atomw[2 * v] : (int)atomw[v];
            val = emb[(size_t)ai * HDIM + i];
        }
        unsigned short d1, d0;
        fx_digits(val, d1, d0);
        const int kc = v >> 6, kk = (v >> 4) & 3, half = (v >> 3) & 1, j = v & 7;
        hTt[bt_idx(kc, 0, kk, half, i, j)] = d1;
        hTt[bt_idx(kc, 1, kk, half, i, j)] = d0;
    } else {                             // ---- h0f: fp32 row-major state ----
        int idx = (b - H0T_BLKS) * 256 + tid;   // < NROW*HDIM
        int v = idx >> 7, i = idx & 127;
        int ai = is64 ? (int)atomw[2 * v] : (int)atomw[v];
        hf[idx] = emb[(size_t)ai * HDIM + i];
    }
}

// ---- GEMM1 (EXACT, barrier-free, LDS-free, 32x32x16 MFMA): agg = A * h ----
// Round-10 structure. Expansion via v_perm_b32 byte-select: sel = t<<8 picks byte 0/1
// (0x00 / 0x3C) of the constant for each output byte -> u32 identical to t*0x3C00.
// Same constant in both perm sources makes the result operand-order independent.
// A frag: row=lane&31, k=(lane>>5)*8+j. C/D: col=lane&31, row=(reg&3)+8*(reg>>2)+4*(lane>>5).
__global__ __launch_bounds__(256, 2) void gemm1_kernel(const unsigned long long* __restrict__ packedT,
                                                       const unsigned short* __restrict__ hTt,
                                                       float* __restrict__ agg) {
    const int m0 = blockIdx.x * 128;
    const int e = blockIdx.y;
    const int kz = blockIdx.z;
    const int tid = threadIdx.x;
    const int lane = tid & 63;
    const int wave = tid >> 6;
    const int l31 = lane & 31;
    const int l1 = lane >> 5;            // half-wave selector
    const int sh2 = l1 * 8;              // bit offset within 16-bit k-group
    const int col = wave * 32 + l31;
    const int kc0 = kz * KCQ;

    f32x16 acc[2][MTI];                  // [pl][mt] = 128 regs
#pragma unroll
    for (int pl = 0; pl < 2; ++pl)
#pragma unroll
        for (int mt = 0; mt < MTI; ++mt) acc[pl][mt] = (f32x16)(0.f);

    const unsigned long long* ap = packedT + ((size_t)e * KC + kc0) * NPAD + m0 + l31;
    const _Float16* bp = (const _Float16*)hTt + (size_t)kc0 * 16384 +
                         (size_t)l1 * 1024 + (size_t)col * 8;

    for (int kc = 0; kc < KCQ; ++kc) {
        unsigned long long aw[MTI];
#pragma unroll
        for (int mt = 0; mt < MTI; ++mt) aw[mt] = ap[mt * 32];

        f16x8 bf[2][4];                  // [pl][kk]
#pragma unroll
        for (int pl = 0; pl < 2; ++pl)
#pragma unroll
            for (int kk = 0; kk < 4; ++kk)
                bf[pl][kk] = *(const f16x8*)(bp + pl * 8192 + kk * 2048);

        ap += NPAD;
        bp += 16384;

#pragma unroll
        for (int kk = 0; kk < 4; ++kk) {
#pragma unroll
            for (int mt = 0; mt < MTI; ++mt) {
                unsigned int w = (kk < 2) ? (unsigned int)aw[mt]
                                          : (unsigned int)(aw[mt] >> 32);
                unsigned int b = (w >> ((kk & 1) * 16 + sh2)) & 0xFFu;
                unsigned int y = b | (b << 15);
                union { unsigned int u[4]; f16x8 h; } Af;
#pragma unroll
                for (int q = 0; q < 4; ++q) {
                    unsigned int t = (y >> (2 * q)) & 0x00010001u;
                    Af.u[q] = __builtin_amdgcn_perm(0x00003C00u, 0x00003C00u, t << 8);
                }
#pragma unroll
                for (int pl = 0; pl < 2; ++pl)
                    acc[pl][mt] = __builtin_amdgcn_mfma_f32_32x32x16_f16(
                        Af.h, bf[pl][kk], acc[pl][mt], 0, 0, 0);
            }
        }
    }

    // epilogue: exact digit combine in double, one optimal fp32 rounding
    float* aggz = agg + (size_t)kz * PART;
#pragma unroll
    for (int mt = 0; mt < MTI; ++mt)
#pragma unroll
        for (int reg = 0; reg < 16; ++reg) {
            int row = (reg & 3) + 8 * (reg >> 2) + 4 * l1;
            int v = m0 + mt * 32 + row;
            if (v < NROW) {
                double d = (double)acc[0][mt][reg] * 2048.0 + (double)acc[1][mt][reg];
                aggz[((size_t)e * NROW + v) * HDIM + col] = (float)(d * (1.0 / 4194304.0));
            }
        }
}

// --- GEMM2 v2 (round-10): msg = Htr*agg (LDS-staged Htr), sigmoid, fp32 out + digits ---
__global__ __launch_bounds__(256) void gemm2_kernel(const float* __restrict__ agg,
                                                    const float* __restrict__ Htr,
                                                    float* __restrict__ hf,       // fp32 state, in/out
                                                    float* __restrict__ outp,     // d_out slice t (fp32)
                                                    unsigned short* __restrict__ hTt) {
    __shared__ float aggs[8][512];             // 16 KB
    __shared__ float hw[64][128];              // 32 KB Htr chunk
    __shared__ unsigned short hs[2][128][8];   // 4 KB digit transpose buffers
    const int tid = threadIdx.x;
    const int v0 = blockIdx.x * 8;             // < 5000 always (625*8 = 5000)

    // stage 8 rows x 512 (sum of 4 kz parts), float4
#pragma unroll
    for (int it = 0; it < 4; ++it) {
        int idx = it * 256 + tid;          // float4 index, 0..1023
        int r = idx >> 7;
        int c = (idx & 127) * 4;
        int e = c >> 7, j = c & 127;
        size_t o = ((size_t)e * NROW + (v0 + r)) * HDIM + j;
        float4 a0 = *(const float4*)&agg[o];
        float4 a1 = *(const float4*)&agg[PART + o];
        float4 a2 = *(const float4*)&agg[2 * PART + o];
        float4 a3 = *(const float4*)&agg[3 * PART + o];
        *(float4*)&aggs[r][c] = make_float4((a0.x + a1.x) + (a2.x + a3.x),
                                            (a0.y + a1.y) + (a2.y + a3.y),
                                            (a0.z + a1.z) + (a2.z + a3.z),
                                            (a0.w + a1.w) + (a2.w + a3.w));
    }
    __syncthreads();

    const int ip = tid & 63;
    const int vg = tid >> 6;             // 0..3 -> rows vg*2, vg*2+1
    const int i0 = ip * 2;
    const int rb = vg * 2;

    float m[2][2][4];                    // [row][i-col][k-lane]
#pragma unroll
    for (int r = 0; r < 2; ++r)
#pragma unroll
        for (int q = 0; q < 2; ++q)
#pragma unroll
            for (int k = 0; k < 4; ++k) m[r][q][k] = 0.f;

    for (int c0 = 0; c0 < 512; c0 += 64) {
        // stage Htr[c0..c0+63][0..127] -> 8192 floats, 256 thr x 8 float4 (coalesced)
#pragma unroll
        for (int p = 0; p < 8; ++p) {
            int idx = p * 256 + tid;           // float4 index, 0..2047
            int cc = idx >> 5;                 // 0..63
            int i4 = (idx & 31) * 4;           // 0..124
            *(float4*)&hw[cc][i4] = *(const float4*)&Htr[(size_t)(c0 + cc) * HDIM + i4];
        }
        __syncthreads();

#pragma unroll 4
        for (int cg = 0; cg < 16; ++cg) {
            int cl = cg * 4;
            float4 q0 = *(const float4*)&aggs[rb][c0 + cl];       // broadcast, conflict-free
            float4 q1 = *(const float4*)&aggs[rb + 1][c0 + cl];
            float a0v[4] = {q0.x, q0.y, q0.z, q0.w};
            float a1v[4] = {q1.x, q1.y, q1.z, q1.w};
#pragma unroll
            for (int k = 0; k < 4; ++k) {
                float2 w = *(const float2*)&hw[cl + k][i0];       // 2-way bank alias = free
                m[0][0][k] += a0v[k] * w.x;
                m[0][1][k] += a0v[k] * w.y;
                m[1][0][k] += a1v[k] * w.x;
                m[1][1][k] += a1v[k] * w.y;
            }
        }
        __syncthreads();                       // protect hw overwrite next chunk
    }

#pragma unroll
    for (int r = 0; r < 2; ++r) {
        int vr = rb + r;
        int v = v0 + vr;
        size_t o = (size_t)v * HDIM + i0;
        float2 hv = *(const float2*)&hf[o];
        float ms0 = (m[r][0][0] + m[r][0][1]) + (m[r][0][2] + m[r][0][3]);
        float ms1 = (m[r][1][0] + m[r][1][1]) + (m[r][1][2] + m[r][1][3]);
        float x0 = hv.x + ms0;
        float x1 = hv.y + ms1;
        float s0 = 1.0f / (1.0f + expf(-x0));
        float s1 = 1.0f / (1.0f + expf(-x1));
        *(float2*)&outp[o] = make_float2(s0, s1);
        *(float2*)&hf[o] = make_float2(s0, s1);
        unsigned short d1a, d0a, d1b, d0b;
        fx_digits(s0, d1a, d0a);
        fx_digits(s1, d1b, d0b);
        hs[0][i0][vr] = d1a;
        hs[1][i0][vr] = d0a;
        hs[0][i0 + 1][vr] = d1b;
        hs[1][i0 + 1][vr] = d0b;
    }
    __syncthreads();
    if (tid < 128) {    // one uint4 (8 k-entries) per plane, coalesced
        const int kc = v0 >> 6, kk = (v0 >> 4) & 3, half = (v0 >> 3) & 1;
#pragma unroll
        for (int pl = 0; pl < 2; ++pl)
            *(uint4*)&hTt[bt_idx(kc, pl, kk, half, tid, 0)] = *(const uint4*)&hs[pl][tid][0];
    }
}

extern "C" void kernel_launch(void* const* d_in, const int* in_sizes, int n_in,
                              void* d_out, int out_size, void* d_ws, size_t ws_size,
                              hipStream_t stream) {
    const unsigned int* atomw = (const unsigned int*)d_in[0];  // int32 OR int64 — sniffed on device
    const int* adjs = (const int*)d_in[1];                     // int32
    // d_in[2] = max_time_steps; reference constant T=4 hard-coded
    const float* emb = (const float*)d_in[3];                  // fp32
    const float* H = (const float*)d_in[4];                    // fp32
    float* out = (float*)d_out;                                // fp32 output

    char* ws = (char*)d_ws;
    unsigned long long* packedT = (unsigned long long*)ws;           // 13,107,200 B (kc-major)
    size_t off = (size_t)4 * KC * NPAD * 8;
    unsigned short* hTt = (unsigned short*)(ws + off);               // 2 planes fragment-major
    off += (size_t)2 * KC * HDIM * 64 * 2;
    float* hf = (float*)(ws + off);                                  // 2,560,000 B
    off += (size_t)NROW * HDIM * 4;
    float* agg = (float*)(ws + off);                                 // 4 parts = 40,960,000 B
    off += (size_t)KZ * PART * 4;
    float* Htr = (float*)(ws + off);                                 // 262,144 B
    off += (size_t)4 * HDIM * HDIM * 4;
    off = (off + 255) & ~(size_t)255;
    unsigned long long* packedR = (unsigned long long*)(ws + off);   // 13,107,200 B (row-major)
    off += (size_t)4 * NPAD * KW * 8;

    prep_pack_kernel<<<dim3(4 * NPAD), 256, 0, stream>>>(adjs, packedR);
    prep_packT_kernel<<<dim3(NPAD / 64, 4), 256, 0, stream>>>(packedR, packedT);
    prep_misc_kernel<<<dim3(H0T_BLKS + H0F_BLKS + HT_BLKS), 256, 0, stream>>>(atomw, emb, H,
                                                                              hTt, hf, Htr);

    for (int t = 0; t < 4; ++t) {
        gemm1_kernel<<<dim3(NPAD / 128, 4, KZ), 256, 0, stream>>>(packedT, hTt, agg);
        gemm2_kernel<<<dim3(NROW / 8), 256, 0, stream>>>(agg, Htr, hf,
                                                         out + (size_t)t * NROW * HDIM, hTt);
    }
}